// Round 1
// 1184.357 us; speedup vs baseline: 1.2018x; 1.2018x over previous
//
#include <hip/hip_runtime.h>

typedef __bf16 bf16x8 __attribute__((ext_vector_type(8)));
typedef float f32x4 __attribute__((ext_vector_type(4)));

__device__ __forceinline__ unsigned short f2b(float f) {
  union { float f; unsigned u; } v; v.f = f;
  unsigned u = v.u;
  u = (u + 0x7fffu + ((u >> 16) & 1u)) >> 16;
  return (unsigned short)u;
}
__device__ __forceinline__ void lds_load16(void* lds, const void* g) {
  __builtin_amdgcn_global_load_lds(
      (const __attribute__((address_space(1))) unsigned int*)g,
      (__attribute__((address_space(3))) unsigned int*)lds, 16, 0, 0);
}

// ---------------- kernel 1: x fp32 -> bf16 (131072 x 200) ----------------
__global__ __launch_bounds__(256) void cvt_x_kernel(const float* __restrict__ x,
                                                    unsigned short* __restrict__ xb) {
  size_t i = (size_t)blockIdx.x * 256 + threadIdx.x;  // chunk of 8 elements
  const float4* xp = (const float4*)(x + i * 8);
  float4 a = xp[0], b = xp[1];
  uint4 o;
  o.x = (unsigned)f2b(a.x) | ((unsigned)f2b(a.y) << 16);
  o.y = (unsigned)f2b(a.z) | ((unsigned)f2b(a.w) << 16);
  o.z = (unsigned)f2b(b.x) | ((unsigned)f2b(b.y) << 16);
  o.w = (unsigned)f2b(b.z) | ((unsigned)f2b(b.w) << 16);
  *(uint4*)(xb + i * 8) = o;
}

// ---------------- kernel 2: build Wt (640 x 224) bf16, zero padded -------
// Wt[n][k] = W[k][n], W = [wq | wk | wv] columns (n<200:wq, <400:wk, <600:wv)
__global__ __launch_bounds__(256) void build_wt_kernel(const float* __restrict__ wq,
                                                       const float* __restrict__ wk,
                                                       const float* __restrict__ wv,
                                                       unsigned short* __restrict__ wt) {
  int i = blockIdx.x * 256 + threadIdx.x;  // over 640*224
  int n = i / 224, k = i - n * 224;
  float val = 0.f;
  if (n < 600 && k < 200) {
    const float* src = (n < 200) ? wq : ((n < 400) ? wk : wv);
    val = src[k * 200 + (n % 200)];
  }
  wt[i] = f2b(val);
}

// ---------------- kernel 3/5: bf16 GEMM, C = A @ Wt^T ---------------------
// A: M x Astride bf16 (logical K=200; k in [200,224) reads junk, but Wt is 0 there)
// Bt: 640 x 224 bf16 (n-major)
// out: either Cb (bf16) or Cf (fp32), row stride Cstride, guard n < Ncols.
// permuteQKV: remap output col n -> h*60 + tile*20 + d (head-major qkv layout).
// LDS chunk swizzle: slot cs in a row holds global k-chunk cs ^ ((row>>1)&3),
// achieved by pre-swizzling the per-lane GLOBAL address (LDS dest stays linear,
// as global_load_lds requires). Fragment reads undo it -> <=2-way banked.
__global__ __launch_bounds__(256) void gemm_kernel(
    const unsigned short* __restrict__ A, long Astride,
    const unsigned short* __restrict__ Bt,
    unsigned short* __restrict__ Cb, float* __restrict__ Cf,
    long Cstride, int Ncols, int permuteQKV) {
  __shared__ unsigned short sA[128 * 32];
  __shared__ unsigned short sB[128 * 32];
  int nb = blockIdx.x, mb = blockIdx.y;
  long mBase = (long)mb * 128;
  int nBase = nb * 128;
  int tid = threadIdx.x;
  int lane = tid & 63, w = tid >> 6;
  int wm = w & 1, wn = w >> 1;
  int frow = lane & 15, fch = lane >> 4;  // k-chunk 0..3 (8 ushorts each)

  f32x4 acc[4][4] = {};

  for (int kk = 0; kk < 7; ++kk) {
    int k0 = kk * 32;
    for (int i = 0; i < 2; ++i) {
      int chunk = i * 256 + w * 64 + lane;   // linear LDS slot (16B units)
      int row = chunk >> 2;
      int cs = chunk & 3;
      int cg = cs ^ ((row >> 1) & 3);        // which global chunk this slot gets
      lds_load16(&sA[(i * 256 + w * 64) * 8], A + (mBase + row) * Astride + k0 + cg * 8);
      lds_load16(&sB[(i * 256 + w * 64) * 8], Bt + (long)(nBase + row) * 224 + k0 + cg * 8);
    }
    __syncthreads();
    bf16x8 fa[4], fb[4];
    for (int i = 0; i < 4; i++) {
      int r = wm * 64 + i * 16 + frow;
      fa[i] = *(const bf16x8*)&sA[r * 32 + (fch ^ ((r >> 1) & 3)) * 8];
    }
    for (int j = 0; j < 4; j++) {
      int r = wn * 64 + j * 16 + frow;
      fb[j] = *(const bf16x8*)&sB[r * 32 + (fch ^ ((r >> 1) & 3)) * 8];
    }
    for (int i = 0; i < 4; i++)
      for (int j = 0; j < 4; j++)
        acc[i][j] = __builtin_amdgcn_mfma_f32_16x16x32_bf16(fa[i], fb[j], acc[i][j], 0, 0, 0);
    __syncthreads();
  }

  int rbase = (lane >> 4) * 4;
  int cN = lane & 15;
  for (int j = 0; j < 4; j++) {
    int n = nBase + wn * 64 + j * 16 + cN;
    if (n < Ncols) {
      long cidx = n;
      if (permuteQKV) {
        int t = n / 200; int rem = n - t * 200;
        int hh = rem / 20; int d = rem - hh * 20;
        cidx = hh * 60 + t * 20 + d;
      }
      for (int i = 0; i < 4; i++) {
        long rowg = mBase + wm * 64 + i * 16 + rbase;
        for (int r = 0; r < 4; r++) {
          long off = (rowg + r) * Cstride + cidx;
          if (Cb) Cb[off] = f2b(acc[i][j][r]);
          else Cf[off] = acc[i][j][r];
        }
      }
    }
  }
}

// ---------------- kernel 4: fused attention per (bf, head) ----------------
// qkv: 131072 x 600 bf16, HEAD-MAJOR rows: [h][q0..19|k0..19|v0..19] x 10.
// attn_out: (1024,10,128,128) fp32.  out_pre: 131072 x 200 bf16.
// Wave wid owns s-rows [32*wid, 32*wid+32). Softmax fully in registers.
__global__ __launch_bounds__(256, 3) void attn_kernel(
    const unsigned short* __restrict__ qkv,
    float* __restrict__ attn_out,
    unsigned short* __restrict__ out_pre) {
  // LDS (bytes):
  //   [0,10240)     sQ [128][40]  (k-cols 20..39 zeroed)
  //   [10240,20480) sK [128][40]
  //   [0,34816)     sS [128][136] P bf16 -- aliases sQ/sK after QK^T barrier
  //   [34816,43520) sV [32][136]  V^T [d][t]; rows 20..31 garbage (outputs unused)
  __shared__ __align__(16) unsigned short smem[21760];
  unsigned short* sS = smem;
  unsigned short* sQ = smem;
  unsigned short* sK = smem + 5120;
  unsigned short* sV = smem + 17408;

  int blk = blockIdx.x;
  int bf = blk / 10, h = blk - bf * 10;
  int tid = threadIdx.x, lane = tid & 63, wid = tid >> 6;
  long rowBase = (long)bf * 128;
  int frow = lane & 15, fk = (lane >> 4) * 8;
  int g4 = (lane >> 4) * 4;

  // zero sQ/sK (incl. k-padding)
  {
    uint4 z = {0, 0, 0, 0};
    uint4* p = (uint4*)smem;
    for (int i = tid; i < 1280; i += 256) p[i] = z;
  }
  __syncthreads();

  // stage: each row's 60 head-cols are contiguous (120B) -> coalesced 8B loads
  for (int c = tid; c < 1920; c += 256) {
    int row = c / 15, j = c - row * 15;
    const unsigned short* g = qkv + (rowBase + row) * 600 + h * 60 + j * 4;
    ushort4 d = *(const ushort4*)g;
    int tile = j / 5, jj = j - tile * 5;
    if (tile < 2) {
      *(ushort4*)((tile == 0 ? sQ : sK) + row * 40 + jj * 4) = d;
    } else {
      int d0 = jj * 4;
      sV[(d0 + 0) * 136 + row] = d.x;
      sV[(d0 + 1) * 136 + row] = d.y;
      sV[(d0 + 2) * 136 + row] = d.z;
      sV[(d0 + 3) * 136 + row] = d.w;
    }
  }
  __syncthreads();

  // QK^T: acc[i][j] -> s = 32*wid+16i+g4+r, t = 16j+frow
  f32x4 acc[2][8] = {};
  {
    bf16x8 qf0 = *(const bf16x8*)&sQ[(wid * 32 + frow) * 40 + fk];
    bf16x8 qf1 = *(const bf16x8*)&sQ[(wid * 32 + 16 + frow) * 40 + fk];
#pragma unroll
    for (int j = 0; j < 8; j++) {
      bf16x8 kf = *(const bf16x8*)&sK[(j * 16 + frow) * 40 + fk];
      acc[0][j] = __builtin_amdgcn_mfma_f32_16x16x32_bf16(qf0, kf, acc[0][j], 0, 0, 0);
      acc[1][j] = __builtin_amdgcn_mfma_f32_16x16x32_bf16(qf1, kf, acc[1][j], 0, 0, 0);
    }
  }
  __syncthreads();  // all waves done reading sQ/sK -> sS may now be written

  // in-register softmax: rows live on 16-lane groups; reduce over j + shfl 1/2/4/8
  const float scale = 0.22360679774997896f;  // 1/sqrt(20)
  long attnBase = (long)blk * 16384;
#pragma unroll
  for (int i = 0; i < 2; i++) {
#pragma unroll
    for (int r = 0; r < 4; r++) {
      float m = acc[i][0][r];
#pragma unroll
      for (int j = 1; j < 8; j++) m = fmaxf(m, acc[i][j][r]);
      m = fmaxf(m, __shfl_xor(m, 1, 64));
      m = fmaxf(m, __shfl_xor(m, 2, 64));
      m = fmaxf(m, __shfl_xor(m, 4, 64));
      m = fmaxf(m, __shfl_xor(m, 8, 64));
      float s = 0.f;
#pragma unroll
      for (int j = 0; j < 8; j++) {
        float e = __expf((acc[i][j][r] - m) * scale);
        acc[i][j][r] = e;
        s += e;
      }
      s += __shfl_xor(s, 1, 64);
      s += __shfl_xor(s, 2, 64);
      s += __shfl_xor(s, 4, 64);
      s += __shfl_xor(s, 8, 64);
      float inv = 1.0f / s;
      int srow = wid * 32 + i * 16 + g4 + r;
      float* gout = attn_out + attnBase + (long)srow * 128 + frow;
      unsigned short* lout = sS + srow * 136 + frow;
#pragma unroll
      for (int j = 0; j < 8; j++) {
        float wgt = acc[i][j][r] * inv;
        gout[j * 16] = wgt;          // fp32 weights, 64B-coalesced runs
        lout[j * 16] = f2b(wgt);     // bf16 P for PV (conflict-free banks)
      }
    }
  }
  // P rows read below are wave-local (written by this wave); lgkmcnt orders it.

  // O = P @ V : accO[i][j], K=128 over 4 slices
  f32x4 accO[2][2] = {};
  int m0 = wid * 32;
#pragma unroll
  for (int ks = 0; ks < 4; ks++) {
    bf16x8 pf0 = *(const bf16x8*)&sS[(m0 + frow) * 136 + ks * 32 + fk];
    bf16x8 pf1 = *(const bf16x8*)&sS[(m0 + 16 + frow) * 136 + ks * 32 + fk];
    bf16x8 vf0 = *(const bf16x8*)&sV[frow * 136 + ks * 32 + fk];
    bf16x8 vf1 = *(const bf16x8*)&sV[(16 + frow) * 136 + ks * 32 + fk];
    accO[0][0] = __builtin_amdgcn_mfma_f32_16x16x32_bf16(pf0, vf0, accO[0][0], 0, 0, 0);
    accO[0][1] = __builtin_amdgcn_mfma_f32_16x16x32_bf16(pf0, vf1, accO[0][1], 0, 0, 0);
    accO[1][0] = __builtin_amdgcn_mfma_f32_16x16x32_bf16(pf1, vf0, accO[1][0], 0, 0, 0);
    accO[1][1] = __builtin_amdgcn_mfma_f32_16x16x32_bf16(pf1, vf1, accO[1][1], 0, 0, 0);
  }
#pragma unroll
  for (int i = 0; i < 2; i++)
#pragma unroll
    for (int j = 0; j < 2; j++) {
      int d = j * 16 + frow;
      if (d < 20) {
        int srow = m0 + i * 16 + g4;
#pragma unroll
        for (int r = 0; r < 4; r++)
          out_pre[(rowBase + srow + r) * 200 + h * 20 + d] = f2b(accO[i][j][r]);
      }
    }
}

extern "C" void kernel_launch(void* const* d_in, const int* in_sizes, int n_in,
                              void* d_out, int out_size, void* d_ws, size_t ws_size,
                              hipStream_t stream) {
  const float* x  = (const float*)d_in[0];
  const float* wq = (const float*)d_in[1];
  const float* wk = (const float*)d_in[2];
  const float* wv = (const float*)d_in[3];
  float* out = (float*)d_out;

  char* ws = (char*)d_ws;
  // layout (bytes):
  //   xb / out_pre (aliased, temporally disjoint): 131072*200*2 = 52,428,800
  //   wt: 640*224*2 = 286,720
  //   qkv: 131072*600*2 = 157,286,400           total ~210 MB
  unsigned short* xb      = (unsigned short*)ws;
  unsigned short* wt      = (unsigned short*)(ws + 52428800);
  unsigned short* qkv     = (unsigned short*)(ws + 52428800 + 286720);
  unsigned short* out_pre = xb;  // reuse: xb dead after QKV GEMM

  // 1) convert x to bf16
  cvt_x_kernel<<<12800, 256, 0, stream>>>(x, xb);
  // 2) build packed transposed weights (serves QKV and final projection)
  build_wt_kernel<<<560, 256, 0, stream>>>(wq, wk, wv, wt);
  // 3) QKV projection -> qkv bf16, head-major column layout
  gemm_kernel<<<dim3(5, 1024), 256, 0, stream>>>(xb, 200, wt, qkv, nullptr, 600, 600, 1);
  // 4) fused attention: writes attn weights (fp32, d_out) + out_pre (bf16)
  attn_kernel<<<10240, 256, 0, stream>>>(qkv, out, out_pre);
  // 5) output projection: (131072 x 200) @ wq -> d_out second chunk (fp32)
  gemm_kernel<<<dim3(2, 1024), 256, 0, stream>>>(out_pre, 200, wt, nullptr,
                                                 out + 167772160L, 200, 200, 0);
}

// Round 2
// 1133.814 us; speedup vs baseline: 1.2553x; 1.0446x over previous
//
#include <hip/hip_runtime.h>

typedef __bf16 bf16x8 __attribute__((ext_vector_type(8)));
typedef float f32x4 __attribute__((ext_vector_type(4)));

__device__ __forceinline__ unsigned short f2b(float f) {
  union { float f; unsigned u; } v; v.f = f;
  unsigned u = v.u;
  u = (u + 0x7fffu + ((u >> 16) & 1u)) >> 16;
  return (unsigned short)u;
}
__device__ __forceinline__ void lds_load16(void* lds, const void* g) {
  __builtin_amdgcn_global_load_lds(
      (const __attribute__((address_space(1))) unsigned int*)g,
      (__attribute__((address_space(3))) unsigned int*)lds, 16, 0, 0);
}

// ---------------- kernel 1: x fp32 -> bf16 (131072 x 200) ----------------
__global__ __launch_bounds__(256) void cvt_x_kernel(const float* __restrict__ x,
                                                    unsigned short* __restrict__ xb) {
  size_t i = (size_t)blockIdx.x * 256 + threadIdx.x;  // chunk of 8 elements
  const float4* xp = (const float4*)(x + i * 8);
  float4 a = xp[0], b = xp[1];
  uint4 o;
  o.x = (unsigned)f2b(a.x) | ((unsigned)f2b(a.y) << 16);
  o.y = (unsigned)f2b(a.z) | ((unsigned)f2b(a.w) << 16);
  o.z = (unsigned)f2b(b.x) | ((unsigned)f2b(b.y) << 16);
  o.w = (unsigned)f2b(b.z) | ((unsigned)f2b(b.w) << 16);
  *(uint4*)(xb + i * 8) = o;
}

// ---------------- kernel 2: build Wt (640 x 224) bf16, zero padded -------
// Wt[n][k] = W[k][n], W = [wq | wk | wv] columns (n<200:wq, <400:wk, <600:wv)
__global__ __launch_bounds__(256) void build_wt_kernel(const float* __restrict__ wq,
                                                       const float* __restrict__ wk,
                                                       const float* __restrict__ wv,
                                                       unsigned short* __restrict__ wt) {
  int i = blockIdx.x * 256 + threadIdx.x;  // over 640*224
  int n = i / 224, k = i - n * 224;
  float val = 0.f;
  if (n < 600 && k < 200) {
    const float* src = (n < 200) ? wq : ((n < 400) ? wk : wv);
    val = src[k * 200 + (n % 200)];
  }
  wt[i] = f2b(val);
}

// ---------------- kernel 3/5: bf16 GEMM, C = A @ Wt^T ---------------------
// A: M x Astride bf16 (logical K=200; k in [200,224) reads junk, but Wt is 0 there)
// Bt: 640 x 224 bf16 (n-major)
// out: either Cb (bf16) or Cf (fp32), row stride Cstride, guard n < Ncols.
// permuteQKV: remap output col n -> h*60 + tile*20 + d (head-major qkv layout).
// Double-buffered LDS: STAGE(next) issued BEFORE compute(cur); a single
// __syncthreads per K-step (its implicit vmcnt(0) drains the in-flight
// global_load_lds AFTER they overlapped the MFMAs). T3 minimum-2-phase.
// LDS chunk swizzle: slot cs in a row holds global k-chunk cs ^ ((row>>1)&3)
// (pre-swizzled GLOBAL address, LDS dest linear as global_load_lds requires);
// fragment reads undo it -> <=2-way banked.
__global__ __launch_bounds__(256, 3) void gemm_kernel(
    const unsigned short* __restrict__ A, long Astride,
    const unsigned short* __restrict__ Bt,
    unsigned short* __restrict__ Cb, float* __restrict__ Cf,
    long Cstride, int Ncols, int permuteQKV) {
  __shared__ unsigned short sA[2][128 * 32];
  __shared__ unsigned short sB[2][128 * 32];
  int nb = blockIdx.x, mb = blockIdx.y;
  long mBase = (long)mb * 128;
  int nBase = nb * 128;
  int tid = threadIdx.x;
  int lane = tid & 63, w = tid >> 6;
  int wm = w & 1, wn = w >> 1;
  int frow = lane & 15, fch = lane >> 4;  // k-chunk 0..3 (8 ushorts each)

  // per-thread staging geometry (constant across steps)
  int chunk0 = w * 64 + lane;          // 16B-chunk id within tile, i=0
  int row0 = chunk0 >> 2, cs0 = chunk0 & 3;
  int cg0 = cs0 ^ ((row0 >> 1) & 3);
  int chunk1 = 256 + chunk0;           // i=1
  int row1 = chunk1 >> 2, cs1 = chunk1 & 3;
  int cg1 = cs1 ^ ((row1 >> 1) & 3);

  f32x4 acc[4][4] = {};

#define STAGE(buf, k0)                                                          \
  do {                                                                          \
    lds_load16(&sA[buf][(w * 64) * 8], A + (mBase + row0) * Astride + (k0) + cg0 * 8); \
    lds_load16(&sB[buf][(w * 64) * 8], Bt + (long)(nBase + row0) * 224 + (k0) + cg0 * 8); \
    lds_load16(&sA[buf][(256 + w * 64) * 8], A + (mBase + row1) * Astride + (k0) + cg1 * 8); \
    lds_load16(&sB[buf][(256 + w * 64) * 8], Bt + (long)(nBase + row1) * 224 + (k0) + cg1 * 8); \
  } while (0)

  STAGE(0, 0);
  __syncthreads();

  int cur = 0;
  for (int kk = 0; kk < 7; ++kk) {
    if (kk < 6) STAGE(cur ^ 1, (kk + 1) * 32);  // loads fly over the MFMAs below
    bf16x8 fa[4], fb[4];
    for (int i = 0; i < 4; i++) {
      int r = wm * 64 + i * 16 + frow;
      fa[i] = *(const bf16x8*)&sA[cur][r * 32 + (fch ^ ((r >> 1) & 3)) * 8];
    }
    for (int j = 0; j < 4; j++) {
      int r = wn * 64 + j * 16 + frow;
      fb[j] = *(const bf16x8*)&sB[cur][r * 32 + (fch ^ ((r >> 1) & 3)) * 8];
    }
    for (int i = 0; i < 4; i++)
      for (int j = 0; j < 4; j++)
        acc[i][j] = __builtin_amdgcn_mfma_f32_16x16x32_bf16(fa[i], fb[j], acc[i][j], 0, 0, 0);
    __syncthreads();  // implicit vmcnt(0): next buffer staged, this buffer free
    cur ^= 1;
  }
#undef STAGE

  int rbase = (lane >> 4) * 4;
  int cN = lane & 15;
  for (int j = 0; j < 4; j++) {
    int n = nBase + wn * 64 + j * 16 + cN;
    if (n < Ncols) {
      long cidx = n;
      if (permuteQKV) {
        int t = n / 200; int rem = n - t * 200;
        int hh = rem / 20; int d = rem - hh * 20;
        cidx = hh * 60 + t * 20 + d;
      }
      for (int i = 0; i < 4; i++) {
        long rowg = mBase + wm * 64 + i * 16 + rbase;
        for (int r = 0; r < 4; r++) {
          long off = (rowg + r) * Cstride + cidx;
          if (Cb) Cb[off] = f2b(acc[i][j][r]);
          else __builtin_nontemporal_store(acc[i][j][r], &Cf[off]);  // final output, never re-read
        }
      }
    }
  }
}

// ---------------- kernel 4: fused attention per (bf, head) ----------------
// qkv: 131072 x 600 bf16, HEAD-MAJOR rows: [h][q0..19|k0..19|v0..19] x 10.
// attn_out: (1024,10,128,128) fp32.  out_pre: 131072 x 200 bf16.
// Wave wid owns s-rows [32*wid, 32*wid+32). Softmax fully in registers.
__global__ __launch_bounds__(256, 3) void attn_kernel(
    const unsigned short* __restrict__ qkv,
    float* __restrict__ attn_out,
    unsigned short* __restrict__ out_pre) {
  // LDS (bytes):
  //   [0,10240)     sQ [128][40]  (k-cols 20..39 zeroed)
  //   [10240,20480) sK [128][40]
  //   [0,34816)     sS [128][136] P bf16 -- aliases sQ/sK after QK^T barrier
  //   [34816,43520) sV [32][136]  V^T [d][t]; rows 20..31 garbage (outputs unused)
  __shared__ __align__(16) unsigned short smem[21760];
  unsigned short* sS = smem;
  unsigned short* sQ = smem;
  unsigned short* sK = smem + 5120;
  unsigned short* sV = smem + 17408;

  int blk = blockIdx.x;
  int bf = blk / 10, h = blk - bf * 10;
  int tid = threadIdx.x, lane = tid & 63, wid = tid >> 6;
  long rowBase = (long)bf * 128;
  int frow = lane & 15, fk = (lane >> 4) * 8;
  int g4 = (lane >> 4) * 4;

  // zero sQ/sK (incl. k-padding)
  {
    uint4 z = {0, 0, 0, 0};
    uint4* p = (uint4*)smem;
    for (int i = tid; i < 1280; i += 256) p[i] = z;
  }
  __syncthreads();

  // stage: each row's 60 head-cols are contiguous (120B) -> coalesced 8B loads
  for (int c = tid; c < 1920; c += 256) {
    int row = c / 15, j = c - row * 15;
    const unsigned short* g = qkv + (rowBase + row) * 600 + h * 60 + j * 4;
    ushort4 d = *(const ushort4*)g;
    int tile = j / 5, jj = j - tile * 5;
    if (tile < 2) {
      *(ushort4*)((tile == 0 ? sQ : sK) + row * 40 + jj * 4) = d;
    } else {
      int d0 = jj * 4;
      sV[(d0 + 0) * 136 + row] = d.x;
      sV[(d0 + 1) * 136 + row] = d.y;
      sV[(d0 + 2) * 136 + row] = d.z;
      sV[(d0 + 3) * 136 + row] = d.w;
    }
  }
  __syncthreads();

  // QK^T: acc[i][j] -> s = 32*wid+16i+g4+r, t = 16j+frow
  f32x4 acc[2][8] = {};
  {
    bf16x8 qf0 = *(const bf16x8*)&sQ[(wid * 32 + frow) * 40 + fk];
    bf16x8 qf1 = *(const bf16x8*)&sQ[(wid * 32 + 16 + frow) * 40 + fk];
#pragma unroll
    for (int j = 0; j < 8; j++) {
      bf16x8 kf = *(const bf16x8*)&sK[(j * 16 + frow) * 40 + fk];
      acc[0][j] = __builtin_amdgcn_mfma_f32_16x16x32_bf16(qf0, kf, acc[0][j], 0, 0, 0);
      acc[1][j] = __builtin_amdgcn_mfma_f32_16x16x32_bf16(qf1, kf, acc[1][j], 0, 0, 0);
    }
  }
  __syncthreads();  // all waves done reading sQ/sK -> sS may now be written

  // in-register softmax: rows live on 16-lane groups; reduce over j + shfl 1/2/4/8
  const float scale = 0.22360679774997896f;  // 1/sqrt(20)
  long attnBase = (long)blk * 16384;
#pragma unroll
  for (int i = 0; i < 2; i++) {
#pragma unroll
    for (int r = 0; r < 4; r++) {
      float m = acc[i][0][r];
#pragma unroll
      for (int j = 1; j < 8; j++) m = fmaxf(m, acc[i][j][r]);
      m = fmaxf(m, __shfl_xor(m, 1, 64));
      m = fmaxf(m, __shfl_xor(m, 2, 64));
      m = fmaxf(m, __shfl_xor(m, 4, 64));
      m = fmaxf(m, __shfl_xor(m, 8, 64));
      float s = 0.f;
#pragma unroll
      for (int j = 0; j < 8; j++) {
        float e = __expf((acc[i][j][r] - m) * scale);
        acc[i][j][r] = e;
        s += e;
      }
      s += __shfl_xor(s, 1, 64);
      s += __shfl_xor(s, 2, 64);
      s += __shfl_xor(s, 4, 64);
      s += __shfl_xor(s, 8, 64);
      float inv = 1.0f / s;
      int srow = wid * 32 + i * 16 + g4 + r;
      float* gout = attn_out + attnBase + (long)srow * 128 + frow;
      unsigned short* lout = sS + srow * 136 + frow;
#pragma unroll
      for (int j = 0; j < 8; j++) {
        float wgt = acc[i][j][r] * inv;
        __builtin_nontemporal_store(wgt, &gout[j * 16]);  // fp32 weights, write-once
        lout[j * 16] = f2b(wgt);     // bf16 P for PV (conflict-free banks)
      }
    }
  }
  // P rows read below are wave-local (written by this wave); lgkmcnt orders it.

  // O = P @ V : accO[i][j], K=128 over 4 slices
  f32x4 accO[2][2] = {};
  int m0 = wid * 32;
#pragma unroll
  for (int ks = 0; ks < 4; ks++) {
    bf16x8 pf0 = *(const bf16x8*)&sS[(m0 + frow) * 136 + ks * 32 + fk];
    bf16x8 pf1 = *(const bf16x8*)&sS[(m0 + 16 + frow) * 136 + ks * 32 + fk];
    bf16x8 vf0 = *(const bf16x8*)&sV[frow * 136 + ks * 32 + fk];
    bf16x8 vf1 = *(const bf16x8*)&sV[(16 + frow) * 136 + ks * 32 + fk];
    accO[0][0] = __builtin_amdgcn_mfma_f32_16x16x32_bf16(pf0, vf0, accO[0][0], 0, 0, 0);
    accO[0][1] = __builtin_amdgcn_mfma_f32_16x16x32_bf16(pf0, vf1, accO[0][1], 0, 0, 0);
    accO[1][0] = __builtin_amdgcn_mfma_f32_16x16x32_bf16(pf1, vf0, accO[1][0], 0, 0, 0);
    accO[1][1] = __builtin_amdgcn_mfma_f32_16x16x32_bf16(pf1, vf1, accO[1][1], 0, 0, 0);
  }
#pragma unroll
  for (int i = 0; i < 2; i++)
#pragma unroll
    for (int j = 0; j < 2; j++) {
      int d = j * 16 + frow;
      if (d < 20) {
        int srow = m0 + i * 16 + g4;
#pragma unroll
        for (int r = 0; r < 4; r++)
          out_pre[(rowBase + srow + r) * 200 + h * 20 + d] = f2b(accO[i][j][r]);
      }
    }
}

extern "C" void kernel_launch(void* const* d_in, const int* in_sizes, int n_in,
                              void* d_out, int out_size, void* d_ws, size_t ws_size,
                              hipStream_t stream) {
  const float* x  = (const float*)d_in[0];
  const float* wq = (const float*)d_in[1];
  const float* wk = (const float*)d_in[2];
  const float* wv = (const float*)d_in[3];
  float* out = (float*)d_out;

  char* ws = (char*)d_ws;
  // layout (bytes):
  //   xb / out_pre (aliased, temporally disjoint): 131072*200*2 = 52,428,800
  //   wt: 640*224*2 = 286,720
  //   qkv: 131072*600*2 = 157,286,400           total ~210 MB
  unsigned short* xb      = (unsigned short*)ws;
  unsigned short* wt      = (unsigned short*)(ws + 52428800);
  unsigned short* qkv     = (unsigned short*)(ws + 52428800 + 286720);
  unsigned short* out_pre = xb;  // reuse: xb dead after QKV GEMM

  // 1) convert x to bf16
  cvt_x_kernel<<<12800, 256, 0, stream>>>(x, xb);
  // 2) build packed transposed weights (serves QKV and final projection)
  build_wt_kernel<<<560, 256, 0, stream>>>(wq, wk, wv, wt);
  // 3) QKV projection -> qkv bf16, head-major column layout
  gemm_kernel<<<dim3(5, 1024), 256, 0, stream>>>(xb, 200, wt, qkv, nullptr, 600, 600, 1);
  // 4) fused attention: writes attn weights (fp32, d_out) + out_pre (bf16)
  attn_kernel<<<10240, 256, 0, stream>>>(qkv, out, out_pre);
  // 5) output projection: (131072 x 200) @ wq -> d_out second chunk (fp32)
  gemm_kernel<<<dim3(2, 1024), 256, 0, stream>>>(out_pre, 200, wt, nullptr,
                                                 out + 167772160L, 200, 200, 0);
}

// Round 4
// 1070.300 us; speedup vs baseline: 1.3298x; 1.0593x over previous
//
#include <hip/hip_runtime.h>

typedef __bf16 bf16x8 __attribute__((ext_vector_type(8)));
typedef float f32x4 __attribute__((ext_vector_type(4)));

__device__ __forceinline__ unsigned short f2b(float f) {
  union { float f; unsigned u; } v; v.f = f;
  unsigned u = v.u;
  u = (u + 0x7fffu + ((u >> 16) & 1u)) >> 16;
  return (unsigned short)u;
}
__device__ __forceinline__ void lds_load16(void* lds, const void* g) {
  __builtin_amdgcn_global_load_lds(
      (const __attribute__((address_space(1))) unsigned int*)g,
      (__attribute__((address_space(3))) unsigned int*)lds, 16, 0, 0);
}
// zero bf16 elements for k>=20 pad (fch = k-chunk 0..3; chunk2 covers k16..23, chunk3 k24..31)
__device__ __forceinline__ bf16x8 maskpad(bf16x8 v, int fch) {
  if (fch >= 2) { v[4] = (__bf16)0.f; v[5] = (__bf16)0.f; v[6] = (__bf16)0.f; v[7] = (__bf16)0.f; }
  if (fch == 3) { v[0] = (__bf16)0.f; v[1] = (__bf16)0.f; v[2] = (__bf16)0.f; v[3] = (__bf16)0.f; }
  return v;
}

// ---------------- kernel 1: x fp32 -> bf16 (131072 x 200) ----------------
__global__ __launch_bounds__(256) void cvt_x_kernel(const float* __restrict__ x,
                                                    unsigned short* __restrict__ xb) {
  size_t i = (size_t)blockIdx.x * 256 + threadIdx.x;  // chunk of 8 elements
  const float4* xp = (const float4*)(x + i * 8);
  float4 a = xp[0], b = xp[1];
  uint4 o;
  o.x = (unsigned)f2b(a.x) | ((unsigned)f2b(a.y) << 16);
  o.y = (unsigned)f2b(a.z) | ((unsigned)f2b(a.w) << 16);
  o.z = (unsigned)f2b(b.x) | ((unsigned)f2b(b.y) << 16);
  o.w = (unsigned)f2b(b.z) | ((unsigned)f2b(b.w) << 16);
  *(uint4*)(xb + i * 8) = o;
}

// ---------------- kernel 2: build Wt (640 x 224) bf16, zero padded -------
__global__ __launch_bounds__(256) void build_wt_kernel(const float* __restrict__ wq,
                                                       const float* __restrict__ wk,
                                                       const float* __restrict__ wv,
                                                       unsigned short* __restrict__ wt) {
  int i = blockIdx.x * 256 + threadIdx.x;  // over 640*224
  int n = i / 224, k = i - n * 224;
  float val = 0.f;
  if (n < 600 && k < 200) {
    const float* src = (n < 200) ? wq : ((n < 400) ? wk : wv);
    val = src[k * 200 + (n % 200)];
  }
  wt[i] = f2b(val);
}

// ---------------- kernel 3/5: bf16 GEMM, C = A @ Wt^T ---------------------
// 1-D grid with chunked XCD swizzle (grid % 8 == 0): blocks sharing an A-tile
// (same mb, NB consecutive nb) run temporally adjacent on the SAME XCD -> the
// A tile's re-reads are L2 hits instead of cross-XCD refetches.
// Double-buffered LDS, STAGE(next) before compute(cur), one barrier per step.
// LDS chunk swizzle via pre-swizzled GLOBAL address (LDS dest linear).
__global__ __launch_bounds__(256, 3) void gemm_kernel(
    const unsigned short* __restrict__ A, long Astride,
    const unsigned short* __restrict__ Bt,
    unsigned short* __restrict__ Cb, float* __restrict__ Cf,
    long Cstride, int Ncols, int permuteQKV, int NB) {
  __shared__ unsigned short sA[2][128 * 32];
  __shared__ unsigned short sB[2][128 * 32];
  int cpx = gridDim.x >> 3;
  int g = ((blockIdx.x & 7) * cpx) + (blockIdx.x >> 3);
  int mb = g / NB, nb = g - mb * NB;
  long mBase = (long)mb * 128;
  int nBase = nb * 128;
  int tid = threadIdx.x;
  int lane = tid & 63, w = tid >> 6;
  int wm = w & 1, wn = w >> 1;
  int frow = lane & 15, fch = lane >> 4;  // k-chunk 0..3 (8 ushorts each)

  int chunk0 = w * 64 + lane;          // 16B-chunk id within tile, i=0
  int row0 = chunk0 >> 2, cs0 = chunk0 & 3;
  int cg0 = cs0 ^ ((row0 >> 1) & 3);
  int chunk1 = 256 + chunk0;           // i=1
  int row1 = chunk1 >> 2, cs1 = chunk1 & 3;
  int cg1 = cs1 ^ ((row1 >> 1) & 3);

  f32x4 acc[4][4] = {};

#define STAGE(buf, k0)                                                          \
  do {                                                                          \
    lds_load16(&sA[buf][(w * 64) * 8], A + (mBase + row0) * Astride + (k0) + cg0 * 8); \
    lds_load16(&sB[buf][(w * 64) * 8], Bt + (long)(nBase + row0) * 224 + (k0) + cg0 * 8); \
    lds_load16(&sA[buf][(256 + w * 64) * 8], A + (mBase + row1) * Astride + (k0) + cg1 * 8); \
    lds_load16(&sB[buf][(256 + w * 64) * 8], Bt + (long)(nBase + row1) * 224 + (k0) + cg1 * 8); \
  } while (0)

  STAGE(0, 0);
  __syncthreads();

  int cur = 0;
  for (int kk = 0; kk < 7; ++kk) {
    if (kk < 6) STAGE(cur ^ 1, (kk + 1) * 32);  // loads fly over the MFMAs below
    bf16x8 fa[4], fb[4];
    for (int i = 0; i < 4; i++) {
      int r = wm * 64 + i * 16 + frow;
      fa[i] = *(const bf16x8*)&sA[cur][r * 32 + (fch ^ ((r >> 1) & 3)) * 8];
    }
    for (int j = 0; j < 4; j++) {
      int r = wn * 64 + j * 16 + frow;
      fb[j] = *(const bf16x8*)&sB[cur][r * 32 + (fch ^ ((r >> 1) & 3)) * 8];
    }
    for (int i = 0; i < 4; i++)
      for (int j = 0; j < 4; j++)
        acc[i][j] = __builtin_amdgcn_mfma_f32_16x16x32_bf16(fa[i], fb[j], acc[i][j], 0, 0, 0);
    __syncthreads();  // implicit vmcnt(0): next buffer staged, this buffer free
    cur ^= 1;
  }
#undef STAGE

  int rbase = (lane >> 4) * 4;
  int cN = lane & 15;
  for (int j = 0; j < 4; j++) {
    int n = nBase + wn * 64 + j * 16 + cN;
    if (n < Ncols) {
      long cidx = n;
      if (permuteQKV) {
        int t = n / 200; int rem = n - t * 200;
        int hh = rem / 20; int d = rem - hh * 20;
        cidx = hh * 60 + t * 20 + d;
      }
      for (int i = 0; i < 4; i++) {
        long rowg = mBase + wm * 64 + i * 16 + rbase;
        for (int r = 0; r < 4; r++) {
          long off = (rowg + r) * Cstride + cidx;
          if (Cb) Cb[off] = f2b(acc[i][j][r]);
          else __builtin_nontemporal_store(acc[i][j][r], &Cf[off]);  // final output
        }
      }
    }
  }
}

// ---------------- kernel 4: fused attention per (bf, head) ----------------
// qkv: 131072 x 600 bf16, HEAD-MAJOR rows: [h][q0..19|k0..19|v0..19] x 10.
// attn_out: (1024,10,128,128) fp32.  out_pre: 131072 x 200 bf16.
// 26.5 KB LDS -> 4+ blocks/CU. Two barriers total. PV in two K-halves so the
// P buffer is half-size and aliases the dead sQ/sK region.
__global__ __launch_bounds__(256, 4) void attn_kernel(
    const unsigned short* __restrict__ qkv,
    float* __restrict__ attn_out,
    unsigned short* __restrict__ out_pre) {
  // LDS (ushort offsets):
  //  [0,3072)      sQ [128][24]  (cols 20..23 garbage -> reg-masked)
  //  [3072,6144)   sK [128][24]
  //  [0,9216)      sS [128][72]  half-P (64 t-cols), aliases sQ/sK after QK^T
  //  [9216,13568)  sV [32][136]  V^T [d][t]; d rows 20..31 garbage (outputs discarded)
  __shared__ __align__(16) unsigned short smem[13568];
  unsigned short* sQ = smem;
  unsigned short* sK = smem + 3072;
  unsigned short* sS = smem;
  unsigned short* sV = smem + 9216;

  int blk = blockIdx.x;
  int bf = blk / 10, h = blk - bf * 10;
  int tid = threadIdx.x, lane = tid & 63, wid = tid >> 6;
  long rowBase = (long)bf * 128;
  int frow = lane & 15, fch = lane >> 4, fk = fch * 8;
  int g4 = fch * 4;
  int m0 = wid * 32;

  // stage: each row's 60 head-cols are contiguous (120B) -> coalesced 8B loads
  for (int c = tid; c < 1920; c += 256) {
    int row = c / 15, j = c - row * 15;
    const unsigned short* g = qkv + (rowBase + row) * 600 + h * 60 + j * 4;
    ushort4 d = *(const ushort4*)g;
    int tile = j / 5, jj = j - tile * 5;
    if (tile < 2) {
      *(ushort4*)((tile == 0 ? sQ : sK) + row * 24 + jj * 4) = d;
    } else {
      int d0 = jj * 4;
      sV[(d0 + 0) * 136 + row] = d.x;
      sV[(d0 + 1) * 136 + row] = d.y;
      sV[(d0 + 2) * 136 + row] = d.z;
      sV[(d0 + 3) * 136 + row] = d.w;
    }
  }
  __syncthreads();

  // QK^T: acc[i][j] -> s = m0+16i+g4+r, t = 16j+(lane&15).  Pad k-cols masked
  // to zero in BOTH operands (0*0, no NaN from garbage LDS).
  f32x4 acc[2][8] = {};
  {
    bf16x8 qf0 = maskpad(*(const bf16x8*)&sQ[(m0 + frow) * 24 + fk], fch);
    bf16x8 qf1 = maskpad(*(const bf16x8*)&sQ[(m0 + 16 + frow) * 24 + fk], fch);
#pragma unroll
    for (int j = 0; j < 8; j++) {
      bf16x8 kf = maskpad(*(const bf16x8*)&sK[(j * 16 + frow) * 24 + fk], fch);
      acc[0][j] = __builtin_amdgcn_mfma_f32_16x16x32_bf16(qf0, kf, acc[0][j], 0, 0, 0);
      acc[1][j] = __builtin_amdgcn_mfma_f32_16x16x32_bf16(qf1, kf, acc[1][j], 0, 0, 0);
    }
  }
  __syncthreads();  // last sQ/sK read -> sS region may be overwritten

  // in-register softmax; acc becomes the normalized weights
  const float scale = 0.22360679774997896f;  // 1/sqrt(20)
  long attnBase = (long)blk * 16384;
#pragma unroll
  for (int i = 0; i < 2; i++) {
#pragma unroll
    for (int r = 0; r < 4; r++) {
      float m = acc[i][0][r];
#pragma unroll
      for (int j = 1; j < 8; j++) m = fmaxf(m, acc[i][j][r]);
      m = fmaxf(m, __shfl_xor(m, 1, 64));
      m = fmaxf(m, __shfl_xor(m, 2, 64));
      m = fmaxf(m, __shfl_xor(m, 4, 64));
      m = fmaxf(m, __shfl_xor(m, 8, 64));
      float s = 0.f;
#pragma unroll
      for (int j = 0; j < 8; j++) {
        float e = __expf((acc[i][j][r] - m) * scale);
        acc[i][j][r] = e;
        s += e;
      }
      s += __shfl_xor(s, 1, 64);
      s += __shfl_xor(s, 2, 64);
      s += __shfl_xor(s, 4, 64);
      s += __shfl_xor(s, 8, 64);
      float inv = 1.0f / s;
      int srow = m0 + i * 16 + g4 + r;
      float* gout = attn_out + attnBase + (long)srow * 128 + frow;
      unsigned short* lout = sS + srow * 72 + frow;
#pragma unroll
      for (int j = 0; j < 8; j++) {
        float wgt = acc[i][j][r] * inv;
        acc[i][j][r] = wgt;
        __builtin_nontemporal_store(wgt, &gout[j * 16]);  // fp32 weights, write-once
      }
#pragma unroll
      for (int j = 0; j < 4; j++) lout[j * 16] = f2b(acc[i][j][r]);  // P cols 0..63
    }
  }

  // O = P @ V in two K-halves (t 0..63, 64..127). P rows are wave-local; the
  // half-buffer refill needs no barrier (same-wave DS ops are in-order).
  f32x4 accO[2][2] = {};
#pragma unroll
  for (int p = 0; p < 2; p++) {
    if (p == 1) {
#pragma unroll
      for (int i = 0; i < 2; i++)
#pragma unroll
        for (int r = 0; r < 4; r++) {
          int srow = m0 + i * 16 + g4 + r;
          unsigned short* lout = sS + srow * 72 + frow;
#pragma unroll
          for (int j = 0; j < 4; j++) lout[j * 16] = f2b(acc[i][4 + j][r]);  // cols 64..127
        }
    }
#pragma unroll
    for (int ks = 0; ks < 2; ks++) {
      bf16x8 pf0 = *(const bf16x8*)&sS[(m0 + frow) * 72 + ks * 32 + fk];
      bf16x8 pf1 = *(const bf16x8*)&sS[(m0 + 16 + frow) * 72 + ks * 32 + fk];
      bf16x8 vf0 = *(const bf16x8*)&sV[frow * 136 + p * 64 + ks * 32 + fk];
      bf16x8 vf1 = *(const bf16x8*)&sV[(16 + frow) * 136 + p * 64 + ks * 32 + fk];
      accO[0][0] = __builtin_amdgcn_mfma_f32_16x16x32_bf16(pf0, vf0, accO[0][0], 0, 0, 0);
      accO[0][1] = __builtin_amdgcn_mfma_f32_16x16x32_bf16(pf0, vf1, accO[0][1], 0, 0, 0);
      accO[1][0] = __builtin_amdgcn_mfma_f32_16x16x32_bf16(pf1, vf0, accO[1][0], 0, 0, 0);
      accO[1][1] = __builtin_amdgcn_mfma_f32_16x16x32_bf16(pf1, vf1, accO[1][1], 0, 0, 0);
    }
  }
#pragma unroll
  for (int i = 0; i < 2; i++)
#pragma unroll
    for (int j = 0; j < 2; j++) {
      int d = j * 16 + frow;
      if (d < 20) {
        int srow = m0 + i * 16 + g4;
#pragma unroll
        for (int r = 0; r < 4; r++)
          out_pre[(rowBase + srow + r) * 200 + h * 20 + d] = f2b(accO[i][j][r]);
      }
    }
}

extern "C" void kernel_launch(void* const* d_in, const int* in_sizes, int n_in,
                              void* d_out, int out_size, void* d_ws, size_t ws_size,
                              hipStream_t stream) {
  const float* x  = (const float*)d_in[0];
  const float* wq = (const float*)d_in[1];
  const float* wk = (const float*)d_in[2];
  const float* wv = (const float*)d_in[3];
  float* out = (float*)d_out;

  char* ws = (char*)d_ws;
  unsigned short* xb      = (unsigned short*)ws;
  unsigned short* wt      = (unsigned short*)(ws + 52428800);
  unsigned short* qkv     = (unsigned short*)(ws + 52428800 + 286720);
  unsigned short* out_pre = xb;  // reuse: xb dead after QKV GEMM

  // 1) convert x to bf16
  cvt_x_kernel<<<12800, 256, 0, stream>>>(x, xb);
  // 2) build packed transposed weights (serves QKV and final projection)
  build_wt_kernel<<<560, 256, 0, stream>>>(wq, wk, wv, wt);
  // 3) QKV projection -> qkv bf16, head-major column layout (grid 5*1024, XCD-swizzled)
  gemm_kernel<<<5120, 256, 0, stream>>>(xb, 200, wt, qkv, nullptr, 600, 600, 1, 5);
  // 4) fused attention: writes attn weights (fp32, d_out) + out_pre (bf16)
  attn_kernel<<<10240, 256, 0, stream>>>(qkv, out, out_pre);
  // 5) output projection: (131072 x 200) @ wq -> d_out second chunk (fp32)
  gemm_kernel<<<2048, 256, 0, stream>>>(out_pre, 200, wt, nullptr,
                                        out + 167772160L, 200, 200, 0, 2);
}